// Round 1
// baseline (5504.387 us; speedup 1.0000x reference)
//
#include <hip/hip_runtime.h>
#include <math.h>

#define NB 512
#define NT 128
#define NN 18
#define NDIM 32
#define NHID 64

typedef _Float16 half_t;
typedef _Float16 f16x4 __attribute__((ext_vector_type(4)));
typedef _Float16 f16x8 __attribute__((ext_vector_type(8)));
typedef float    f32x4 __attribute__((ext_vector_type(4)));

__device__ __forceinline__ float fast_sigmoid(float x) {
    return 1.f / (1.f + __expf(-x));
}
__device__ __forceinline__ float fast_tanh(float x) {
    float xc = fminf(fmaxf(x, -15.f), 15.f);
    float e  = __expf(2.f * xc);
    return (e - 1.f) / (e + 1.f);
}
__device__ __forceinline__ f32x4 mfma16(f16x8 a, f16x8 b, f32x4 c) {
    return __builtin_amdgcn_mfma_f32_16x16x32_f16(a, b, c, 0, 0, 0);
}

// Persistent per-wave weight fragments: loaded ONCE before the t-loop
// (they are time-invariant), kept in VGPRs for all 128 steps.
template <int KT, int CMAX> struct BW { f16x8 v[CMAX][KT]; };

template <int KT, int CMAX>
__device__ __forceinline__ void load_b(BW<KT, CMAX>& Bw, const f16x8* __restrict__ Wf,
                                       int NTW, int nt0, int cnt, int lane) {
#pragma unroll
    for (int i = 0; i < CMAX; ++i) {
        if (i < cnt) {
#pragma unroll
            for (int kt = 0; kt < KT; ++kt) Bw.v[i][kt] = Wf[(kt * NTW + nt0 + i) * 64 + lane];
        } else {
            f16x8 z = {0, 0, 0, 0, 0, 0, 0, 0};
#pragma unroll
            for (int kt = 0; kt < KT; ++kt) Bw.v[i][kt] = z;
        }
    }
}

// ---------------------------------------------------------------------------
// MM1: Y(18 x 5*ncol) = Z(18 x C) * W'(C x 5*ncol). B-frags come from the
// persistent register set (no global traffic in the t-loop).
// SCATTER RULE (race fix): mt=0 writes rows 0..15 (all quads); mt=1 writes
// ONLY quad==0 (rows 16..19). Rows 20..23 / 120..127 stay zero from init.
// ---------------------------------------------------------------------------
template <int KT, int CMAX>
__device__ __forceinline__ void mm1_reg(const BW<KT, CMAX>& Bw, int ncs,
                                        const half_t* Zf, half_t* Yf,
                                        int nt0, int cnt, int lane) {
    f16x8 A[2 * KT];
#pragma unroll
    for (int kt = 0; kt < KT; ++kt) {
        A[kt * 2 + 0] = *(const f16x8*)(Zf + (kt * 2 + 0) * 512 + lane * 8);
        A[kt * 2 + 1] = *(const f16x8*)(Zf + (kt * 2 + 1) * 512 + lane * 8);
    }
    const int quad = lane >> 4, ln = lane & 15;
#pragma unroll
    for (int i = 0; i < CMAX; ++i) {
        if (i < cnt) {
            const int ntp = nt0 + i;
            f32x4 ac0 = {0.f, 0.f, 0.f, 0.f};
            f32x4 ac1 = {0.f, 0.f, 0.f, 0.f};
#pragma unroll
            for (int kt = 0; kt < KT; ++kt) {
                ac0 = mfma16(A[kt * 2 + 0], Bw.v[i][kt], ac0);
                ac1 = mfma16(A[kt * 2 + 1], Bw.v[i][kt], ac1);
            }
            const int m  = ntp >> ncs;            // ncol16 = 1<<ncs
            const int ot = ntp - (m << ncs);
            // mt=0: rows k = 24m + quad*4 + r (0..15)
            {
                const int k0 = 24 * m + quad * 4;
                f16x4 pk;
#pragma unroll
                for (int r = 0; r < 4; ++r) pk[r] = (half_t)ac0[r];
                *(f16x4*)(Yf + ((k0 >> 5) * 8 + ot) * 512 +
                          (((((k0 >> 3) & 3) << 4) | ln) * 8) + (k0 & 7)) = pk;
            }
            // mt=1: only quad 0 -> rows 16..19 (16,17 real; 18,19 zero)
            if (quad == 0) {
                const int k0 = 24 * m + 16;       // multiple of 8
                f16x4 pk;
#pragma unroll
                for (int r = 0; r < 4; ++r) pk[r] = (half_t)ac1[r];
                *(f16x4*)(Yf + ((k0 >> 5) * 8 + ot) * 512 +
                          (((((k0 >> 3) & 3) << 4) | ln) * 8) + (k0 & 7)) = pk;
            }
        }
    }
}

// ---------------------------------------------------------------------------
// MM2 gate: ru(18 x 128) = Pcat(18 x 120pad128) * Ycat + bias -> sigmoid.
// Pcat A-frags live in persistent registers (PA); bias preloaded per lane.
// o<64: r -> write r*h into Z frags; o>=64: u -> ubuf. Does NOT read Zf.
// ---------------------------------------------------------------------------
__device__ __forceinline__ void mm2_gate(const f16x8 (&PA)[8], const half_t* Yf,
                                         half_t* Zf, float bias,
                                         const float (*h)[NHID], float (*ub)[NHID],
                                         int DIMin, int wv, int lane) {
    const int nt2 = wv, quad = lane >> 4, ln = lane & 15;
    f32x4 a0 = {0.f, 0.f, 0.f, 0.f};
    f32x4 a1 = {0.f, 0.f, 0.f, 0.f};
#pragma unroll
    for (int kt = 0; kt < 4; ++kt) {
        f16x8 B = *(const f16x8*)(Yf + (kt * 8 + nt2) * 512 + lane * 8);
        a0 = mfma16(PA[kt * 2 + 0], B, a0);
        a1 = mfma16(PA[kt * 2 + 1], B, a1);
    }
    const int o = nt2 * 16 + ln;
    if (o < NHID) {
        const int kZ = DIMin + o;
        const int base = ((kZ >> 5) * 2) * 512 + (((kZ >> 3) & 3) << 4) * 8 + (kZ & 7);
#pragma unroll
        for (int r = 0; r < 4; ++r) {
            int n = quad * 4 + r;
            float rv = fast_sigmoid(a0[r] + bias);
            Zf[base + (n & 15) * 8] = (half_t)(rv * h[n][o]);
        }
        if (quad == 0) {
#pragma unroll
            for (int r = 0; r < 2; ++r) {
                int n = 16 + r;
                float rv = fast_sigmoid(a1[r] + bias);
                Zf[base + 512 + (n & 15) * 8] = (half_t)(rv * h[n][o]);
            }
        }
    } else {
        const int oc = o - NHID;
#pragma unroll
        for (int r = 0; r < 4; ++r) ub[quad * 4 + r][oc] = fast_sigmoid(a0[r] + bias);
        if (quad == 0) {
#pragma unroll
            for (int r = 0; r < 2; ++r) ub[16 + r][oc] = fast_sigmoid(a1[r] + bias);
        }
    }
}

// ---------------------------------------------------------------------------
// MM2 cand: c = tanh(Pcat * Ycat + bias); h = u*h + (1-u)*c.
// Wave w: nt2 = w&3, mtA = w>>2. PAc = the wave's 4 Pcat frags (persistent).
// ---------------------------------------------------------------------------
__device__ __forceinline__ void mm2_cand(const f16x8 (&PAc)[4], const half_t* Yf,
                                         float bias, float (*h)[NHID],
                                         const float (*ub)[NHID], int wv, int lane) {
    const int nt2 = wv & 3, mtA = wv >> 2;
    const int quad = lane >> 4;
    f32x4 a = {0.f, 0.f, 0.f, 0.f};
#pragma unroll
    for (int kt = 0; kt < 4; ++kt) {
        f16x8 B = *(const f16x8*)(Yf + (kt * 8 + nt2) * 512 + lane * 8);
        a = mfma16(PAc[kt], B, a);
    }
    const int o = nt2 * 16 + (lane & 15);
#pragma unroll
    for (int r = 0; r < 4; ++r) {
        int n = mtA * 16 + quad * 4 + r;
        if (n < NN) {
            float cv = fast_tanh(a[r] + bias);
            float uv = ub[n][o];
            h[n][o] = uv * h[n][o] + (1.f - uv) * cv;
        }
    }
}

// ---------------------------------------------------------------------------
// Weight pack: W[(m*C + c)][o] fp32 -> MM1 B-frag order fp16.
// ---------------------------------------------------------------------------
__global__ void pack_w(const float* __restrict__ W, f16x8* __restrict__ out,
                       int KT, int NTW, int ncol, int C) {
    int idx = blockIdx.x * blockDim.x + threadIdx.x;
    if (idx >= KT * NTW * 64) return;
    int lane = idx & 63, f = idx >> 6;
    int kt = f / NTW, ntp = f - kt * NTW;
    int ncol16 = ncol >> 4;
    int m = ntp / ncol16, ot = ntp - m * ncol16;
    int o = ot * 16 + (lane & 15);
    f16x8 v;
#pragma unroll
    for (int jj = 0; jj < 8; ++jj) {
        int c = kt * 32 + ((lane >> 4) << 3) + jj;
        v[jj] = (half_t)W[(m * C + c) * ncol + o];
    }
    out[idx] = v;
}

// ---------------------------------------------------------------------------
// Pcat pack: A-frag order fp16 for MM2.
// ---------------------------------------------------------------------------
__global__ void pack_pcat(const float* __restrict__ sup, f16x8* __restrict__ out) {
    int tid = threadIdx.x;                 // 512 threads, 1 block
    int lane = tid & 63, fidx = tid >> 6;  // 8 frags: (kt2, mtA)
    int mtA = fidx & 1, kt2 = fidx >> 1;
    int n = mtA * 16 + (lane & 15);
    f16x8 v;
#pragma unroll 1
    for (int jj = 0; jj < 8; ++jj) {
        int k = kt2 * 32 + ((lane >> 4) << 3) + jj;
        int m = k / 24, j = k - m * 24;
        float val = 0.f;
        if (n < NN && j < NN && m < 5) {
            if (m == 0)      val = (n == j) ? 1.f : 0.f;
            else if (m == 1) val = sup[0 * 324 + n * 18 + j];
            else if (m == 3) val = sup[1 * 324 + n * 18 + j];
            else {
                const float* S = sup + ((m == 2) ? 0 : 1) * 324;
                float acc = 0.f;
                for (int l = 0; l < NN; ++l) acc += S[n * 18 + l] * S[l * 18 + j];
                val = 2.f * acc - ((n == j) ? 1.f : 0.f);
            }
        }
        v[jj] = (half_t)val;
    }
    out[fidx * 64 + lane] = v;
}

// ---------------------------------------------------------------------------
// Persistent per-batch kernel: 512 blocks x 512 threads (8 waves).
// LDS: Zf 8K + Yf 32K + h_a/h_b/ubuf 13.5K = 53.5K -> 2 blocks/CU.
// All mm1 B-frags + Pcat A-frags + biases are loaded once into registers
// before the t-loop (t-invariant) -> zero weight traffic in the main loop.
// ---------------------------------------------------------------------------
__global__ __launch_bounds__(512, 4) void dcrnn_kernel(
    const float* __restrict__ x,
    const f16x8* __restrict__ wg0, const float* __restrict__ bg0,
    const f16x8* __restrict__ wc0, const float* __restrict__ bc0,
    const f16x8* __restrict__ wg1, const float* __restrict__ bg1,
    const f16x8* __restrict__ wc1, const float* __restrict__ bc1,
    const f16x8* __restrict__ Pf,
    const float* __restrict__ fcw, const float* __restrict__ fcb,
    float* __restrict__ out) {
    __shared__ __align__(16) half_t Zf[8 * 512];    // Z as A-frags (kt*2+mt)
    __shared__ __align__(16) half_t Yf[32 * 512];   // Ycat as B-frags (kt2*8+ot)
    __shared__ float h_a[NN][NHID];
    __shared__ float h_b[NN][NHID];
    __shared__ float ubuf[NN][NHID];

    const int tid  = threadIdx.x;
    const int lane = tid & 63;
    const int wv   = tid >> 6;
    const int b    = blockIdx.x;

    // one-time init: zero Z/Y frag pads (pad stays zero forever), zero h
    {
        f16x8 z = {0, 0, 0, 0, 0, 0, 0, 0};
        ((f16x8*)Zf)[tid] = z;
#pragma unroll
        for (int i = 0; i < 4; ++i) ((f16x8*)Yf)[tid + i * 512] = z;
        for (int i = tid; i < NN * NHID; i += 512) {
            ((float*)h_a)[i] = 0.f;
            ((float*)h_b)[i] = 0.f;
        }
    }

    // mm1 wave partitions: gate NTW=40 -> 5/wave; cand NTW=20 -> 3,3,3,3,2,2,2,2
    const int gnt0 = wv * 5;
    const int cnt0 = (wv < 4) ? wv * 3 : 12 + (wv - 4) * 2;
    const int ccnt = (wv < 4) ? 3 : 2;
    const int mtA  = wv >> 2;
    const int ln   = lane & 15;

    // ---- persistent register state (t-invariant) ----
    BW<3, 5> Bg0; BW<3, 3> Bc0; BW<4, 5> Bg1; BW<4, 3> Bc1;
    load_b(Bg0, wg0, 40, gnt0, 5, lane);
    load_b(Bc0, wc0, 20, cnt0, ccnt, lane);
    load_b(Bg1, wg1, 40, gnt0, 5, lane);
    load_b(Bc1, wc1, 20, cnt0, ccnt, lane);
    f16x8 PA[8];
#pragma unroll
    for (int k = 0; k < 8; ++k) PA[k] = Pf[k * 64 + lane];
    f16x8 PAc[4];
#pragma unroll
    for (int kt = 0; kt < 4; ++kt) PAc[kt] = Pf[(kt * 2 + mtA) * 64 + lane];
    const float bgt0 = bg0[wv * 16 + ln];
    const float bct0 = bc0[(wv & 3) * 16 + ln];
    const float bgt1 = bg1[wv * 16 + ln];
    const float bct1 = bc1[(wv & 3) * 16 + ln];

    __syncthreads();

    const float* xb = x + (size_t)b * NT * NN * NDIM;

    for (int t = 0; t < NT; ++t) {
        const float* xt = xb + (size_t)t * NN * NDIM;

        // ======== layer 0: C=96 (KT=3), DIMin=32 ========
        // stage A: Zf <- [x | h_a]
        for (int idx = tid; idx < NN * 12; idx += 512) {
            int n = idx / 12, c8 = idx - n * 12;
            int c = c8 * 8;
            const float* src = (c < NDIM) ? &xt[n * NDIM + c] : &h_a[n][c - NDIM];
            f16x8 o8;
#pragma unroll
            for (int q = 0; q < 8; ++q) o8[q] = (half_t)src[q];
            *(f16x8*)(Zf + ((c8 >> 2) * 2 + (n >> 4)) * 512 +
                      (((c8 & 3) << 4) | (n & 15)) * 8) = o8;
        }
        __syncthreads();
        mm1_reg(Bg0, 3, Zf, Yf, gnt0, 5, lane);
        __syncthreads();
        mm2_gate(PA, Yf, Zf, bgt0, h_a, ubuf, 32, wv, lane);
        __syncthreads();
        mm1_reg(Bc0, 2, Zf, Yf, cnt0, ccnt, lane);
        __syncthreads();
        mm2_cand(PAc, Yf, bct0, h_a, ubuf, wv, lane);
        __syncthreads();

        // ======== layer 1: C=128 (KT=4), DIMin=64 ========
        for (int idx = tid; idx < NN * 16; idx += 512) {
            int n = idx >> 4, c8 = idx & 15;
            int c = c8 * 8;
            const float* src = (c < NHID) ? &h_a[n][c] : &h_b[n][c - NHID];
            f16x8 o8;
#pragma unroll
            for (int q = 0; q < 8; ++q) o8[q] = (half_t)src[q];
            *(f16x8*)(Zf + ((c8 >> 2) * 2 + (n >> 4)) * 512 +
                      (((c8 & 3) << 4) | (n & 15)) * 8) = o8;
        }
        __syncthreads();
        mm1_reg(Bg1, 3, Zf, Yf, gnt0, 5, lane);
        __syncthreads();
        mm2_gate(PA, Yf, Zf, bgt1, h_b, ubuf, 64, wv, lane);
        __syncthreads();
        mm1_reg(Bc1, 2, Zf, Yf, cnt0, ccnt, lane);
        __syncthreads();
        mm2_cand(PAc, Yf, bct1, h_b, ubuf, wv, lane);
        __syncthreads();
    }

    // ---- output head: out[b] = max_n (relu(h_b[n]) . fcw + fcb) ----
    if (tid < NN) {
        float acc = fcb[0];
#pragma unroll 1
        for (int c = 0; c < NHID; ++c)
            acc = fmaf(fmaxf(h_b[tid][c], 0.f), fcw[c], acc);
        ((float*)ubuf)[tid] = acc;
    }
    __syncthreads();
    if (tid == 0) {
        float m = -1e30f;
#pragma unroll
        for (int n = 0; n < NN; ++n) m = fmaxf(m, ((float*)ubuf)[n]);
        out[b] = m;
    }
}

extern "C" void kernel_launch(void* const* d_in, const int* in_sizes, int n_in,
                              void* d_out, int out_size, void* d_ws, size_t ws_size,
                              hipStream_t stream) {
    const float* x   = (const float*)d_in[0];
    const float* sup = (const float*)d_in[1];
    const float* wg0 = (const float*)d_in[2];
    const float* bg0 = (const float*)d_in[3];
    const float* wc0 = (const float*)d_in[4];
    const float* bc0 = (const float*)d_in[5];
    const float* wg1 = (const float*)d_in[6];
    const float* bg1 = (const float*)d_in[7];
    const float* wc1 = (const float*)d_in[8];
    const float* bc1 = (const float*)d_in[9];
    const float* fcw = (const float*)d_in[10];
    const float* fcb = (const float*)d_in[11];
    float* out = (float*)d_out;

    // ws: packed fp16 MM1 B-frags + Pcat A-frags (438272 B total)
    char* ws = (char*)d_ws;
    f16x8* wg0p = (f16x8*)(ws + 0);        // KT=3, NTW=40 -> 122880 B
    f16x8* wc0p = (f16x8*)(ws + 122880);   // KT=3, NTW=20 ->  61440 B
    f16x8* wg1p = (f16x8*)(ws + 184320);   // KT=4, NTW=40 -> 163840 B
    f16x8* wc1p = (f16x8*)(ws + 348160);   // KT=4, NTW=20 ->  81920 B
    f16x8* pfp  = (f16x8*)(ws + 430080);   // 8 frags      ->   8192 B

    pack_w<<<dim3(30), dim3(256), 0, stream>>>(wg0, wg0p, 3, 40, 128, 96);
    pack_w<<<dim3(15), dim3(256), 0, stream>>>(wc0, wc0p, 3, 20, 64, 96);
    pack_w<<<dim3(40), dim3(256), 0, stream>>>(wg1, wg1p, 4, 40, 128, 128);
    pack_w<<<dim3(20), dim3(256), 0, stream>>>(wc1, wc1p, 4, 20, 64, 128);
    pack_pcat<<<dim3(1), dim3(512), 0, stream>>>(sup, pfp);

    dcrnn_kernel<<<dim3(NB), dim3(512), 0, stream>>>(
        x, wg0p, bg0, wc0p, bc0, wg1p, bg1, wc1p, bc1, pfp, fcw, fcb, out);
}

// Round 2
// 4323.824 us; speedup vs baseline: 1.2730x; 1.2730x over previous
//
#include <hip/hip_runtime.h>
#include <math.h>

#define NB 512
#define NT 128
#define NN 18
#define NDIM 32
#define NHID 64

typedef _Float16 half_t;
typedef _Float16 f16x4 __attribute__((ext_vector_type(4)));
typedef _Float16 f16x8 __attribute__((ext_vector_type(8)));
typedef float    f32x4 __attribute__((ext_vector_type(4)));

__device__ __forceinline__ float fast_sigmoid(float x) {
    return __builtin_amdgcn_rcpf(1.f + __expf(-x));
}
__device__ __forceinline__ float fast_tanh(float x) {
    float xc = fminf(fmaxf(x, -15.f), 15.f);
    float e  = __expf(2.f * xc);
    return 1.f - 2.f * __builtin_amdgcn_rcpf(e + 1.f);
}
__device__ __forceinline__ f32x4 mfma16(f16x8 a, f16x8 b, f32x4 c) {
    return __builtin_amdgcn_mfma_f32_16x16x32_f16(a, b, c, 0, 0, 0);
}

// lgkm-only barrier: drains LDS ops (all cross-wave traffic in the t-loop is
// LDS) but leaves global weight prefetches IN FLIGHT across the barrier.
// __syncthreads() would emit s_waitcnt vmcnt(0) and kill the weight pipeline.
#define BAR_LGKM() do { asm volatile("s_waitcnt lgkmcnt(0)" ::: "memory"); \
                        __builtin_amdgcn_s_barrier(); } while (0)

// Prefetch struct: first NPF columns' B-frags, issued one phase EARLY
// (before the barrier preceding the mm1 that consumes them).
template <int KT, int NPF> struct BPre { f16x8 v[NPF][KT]; };

template <int KT, int NPF>
__device__ __forceinline__ void mm1_pre(BPre<KT, NPF>& P, const f16x8* __restrict__ Wf,
                                        int NTW, int nt0, int cnt, int lane) {
#pragma unroll
    for (int i = 0; i < NPF; ++i) {
        const int col = nt0 + ((i < cnt) ? i : (cnt - 1));  // clamp (dup harmless, unused)
#pragma unroll
        for (int kt = 0; kt < KT; ++kt) P.v[i][kt] = Wf[(kt * NTW + col) * 64 + lane];
    }
}

// ---------------------------------------------------------------------------
// MM1: Y(18 x 5*ncol) = Z(18 x C) * W'(C x 5*ncol). Fully unrolled; first
// min(NPF,CNT) B-columns come from the cross-barrier prefetch, the rest are
// streamed at depth NPF inside the loop.
// SCATTER RULE (race fix): mt=0 writes rows 0..15 (all quads); mt=1 writes
// ONLY quad==0 (rows 16..19). Rows 20..23 / 120..127 stay zero from init.
// ---------------------------------------------------------------------------
template <int KT, int NCS, int CNT, int NPF>
__device__ __forceinline__ void mm1_main(const BPre<KT, NPF>& P,
                                         const f16x8* __restrict__ Wf, int NTW,
                                         const half_t* Zf, half_t* Yf,
                                         int nt0, int lane) {
    constexpr int PF = (NPF < CNT) ? NPF : CNT;
    f16x8 A[2 * KT];
#pragma unroll
    for (int kt = 0; kt < KT; ++kt) {
        A[kt * 2 + 0] = *(const f16x8*)(Zf + (kt * 2 + 0) * 512 + lane * 8);
        A[kt * 2 + 1] = *(const f16x8*)(Zf + (kt * 2 + 1) * 512 + lane * 8);
    }
    f16x8 B[CNT][KT];
#pragma unroll
    for (int i = 0; i < PF; ++i)
#pragma unroll
        for (int kt = 0; kt < KT; ++kt) B[i][kt] = P.v[i][kt];

    const int quad = lane >> 4, ln = lane & 15;
#pragma unroll
    for (int i = 0; i < CNT; ++i) {
        if (i + PF < CNT) {  // compile-time under full unroll
#pragma unroll
            for (int kt = 0; kt < KT; ++kt)
                B[i + PF][kt] = Wf[(kt * NTW + nt0 + i + PF) * 64 + lane];
        }
        const int ntp = nt0 + i;
        f32x4 ac0 = {0.f, 0.f, 0.f, 0.f};
        f32x4 ac1 = {0.f, 0.f, 0.f, 0.f};
#pragma unroll
        for (int kt = 0; kt < KT; ++kt) {
            ac0 = mfma16(A[kt * 2 + 0], B[i][kt], ac0);
            ac1 = mfma16(A[kt * 2 + 1], B[i][kt], ac1);
        }
        const int m  = ntp >> NCS;            // ncol16 = 1<<NCS
        const int ot = ntp - (m << NCS);
        // mt=0: rows k = 24m + quad*4 + r (0..15)
        {
            const int k0 = 24 * m + quad * 4;
            f16x4 pk;
#pragma unroll
            for (int r = 0; r < 4; ++r) pk[r] = (half_t)ac0[r];
            *(f16x4*)(Yf + ((k0 >> 5) * 8 + ot) * 512 +
                      (((((k0 >> 3) & 3) << 4) | ln) * 8) + (k0 & 7)) = pk;
        }
        // mt=1: only quad 0 -> rows 16..19 (16,17 real; 18,19 zero)
        if (quad == 0) {
            const int k0 = 24 * m + 16;       // multiple of 8
            f16x4 pk;
#pragma unroll
            for (int r = 0; r < 4; ++r) pk[r] = (half_t)ac1[r];
            *(f16x4*)(Yf + ((k0 >> 5) * 8 + ot) * 512 +
                      (((((k0 >> 3) & 3) << 4) | ln) * 8) + (k0 & 7)) = pk;
        }
    }
}

// ---------------------------------------------------------------------------
// MM2 gate: ru(18 x 128) = Pcat(18 x 120pad128) * Ycat + bias -> sigmoid.
// o<64: r -> write r*h into Z frags; o>=64: u -> ubuf. Does NOT read Zf.
// ---------------------------------------------------------------------------
__device__ __forceinline__ void mm2_gate(const half_t* Pc, const half_t* Yf,
                                         half_t* Zf, float bias,
                                         const float (*h)[NHID], float (*ub)[NHID],
                                         int DIMin, int wv, int lane) {
    const int nt2 = wv, quad = lane >> 4, ln = lane & 15;
    f32x4 a0 = {0.f, 0.f, 0.f, 0.f};
    f32x4 a1 = {0.f, 0.f, 0.f, 0.f};
#pragma unroll
    for (int kt = 0; kt < 4; ++kt) {
        f16x8 B  = *(const f16x8*)(Yf + (kt * 8 + nt2) * 512 + lane * 8);
        f16x8 A0 = *(const f16x8*)(Pc + (kt * 2 + 0) * 512 + lane * 8);
        f16x8 A1 = *(const f16x8*)(Pc + (kt * 2 + 1) * 512 + lane * 8);
        a0 = mfma16(A0, B, a0);
        a1 = mfma16(A1, B, a1);
    }
    const int o = nt2 * 16 + ln;
    if (o < NHID) {
        const int kZ = DIMin + o;
        const int base = ((kZ >> 5) * 2) * 512 + (((kZ >> 3) & 3) << 4) * 8 + (kZ & 7);
#pragma unroll
        for (int r = 0; r < 4; ++r) {
            int n = quad * 4 + r;
            float rv = fast_sigmoid(a0[r] + bias);
            Zf[base + (n & 15) * 8] = (half_t)(rv * h[n][o]);
        }
        if (quad == 0) {
#pragma unroll
            for (int r = 0; r < 2; ++r) {
                int n = 16 + r;
                float rv = fast_sigmoid(a1[r] + bias);
                Zf[base + 512 + (n & 15) * 8] = (half_t)(rv * h[n][o]);
            }
        }
    } else {
        const int oc = o - NHID;
#pragma unroll
        for (int r = 0; r < 4; ++r) ub[quad * 4 + r][oc] = fast_sigmoid(a0[r] + bias);
        if (quad == 0) {
#pragma unroll
            for (int r = 0; r < 2; ++r) ub[16 + r][oc] = fast_sigmoid(a1[r] + bias);
        }
    }
}

// ---------------------------------------------------------------------------
// MM2 cand: c = tanh(Pcat * Ycat + bias); h = u*h + (1-u)*c.
// Wave w: nt2 = w&3, mtA = w>>2.
// ---------------------------------------------------------------------------
__device__ __forceinline__ void mm2_cand(const half_t* Pc, const half_t* Yf,
                                         float bias, float (*h)[NHID],
                                         const float (*ub)[NHID], int wv, int lane) {
    const int nt2 = wv & 3, mtA = wv >> 2;
    const int quad = lane >> 4;
    f32x4 a = {0.f, 0.f, 0.f, 0.f};
#pragma unroll
    for (int kt = 0; kt < 4; ++kt) {
        f16x8 B = *(const f16x8*)(Yf + (kt * 8 + nt2) * 512 + lane * 8);
        f16x8 A = *(const f16x8*)(Pc + (kt * 2 + mtA) * 512 + lane * 8);
        a = mfma16(A, B, a);
    }
    const int o = nt2 * 16 + (lane & 15);
#pragma unroll
    for (int r = 0; r < 4; ++r) {
        int n = mtA * 16 + quad * 4 + r;
        if (n < NN) {
            float cv = fast_tanh(a[r] + bias);
            float uv = ub[n][o];
            h[n][o] = uv * h[n][o] + (1.f - uv) * cv;
        }
    }
}

// stage A (layer 0): Zf <- [x | h_a] as A-frags
__device__ __forceinline__ void stage0(const float* __restrict__ xt,
                                       const float (*h)[NHID], half_t* Zf, int tid) {
    for (int idx = tid; idx < NN * 12; idx += 512) {
        int n = idx / 12, c8 = idx - n * 12;
        int c = c8 * 8;
        const float* src = (c < NDIM) ? &xt[n * NDIM + c] : &h[n][c - NDIM];
        f16x8 o8;
#pragma unroll
        for (int q = 0; q < 8; ++q) o8[q] = (half_t)src[q];
        *(f16x8*)(Zf + ((c8 >> 2) * 2 + (n >> 4)) * 512 +
                  (((c8 & 3) << 4) | (n & 15)) * 8) = o8;
    }
}

// stage A (layer 1): Zf <- [h_a | h_b] as A-frags
__device__ __forceinline__ void stage1(const float (*ha)[NHID], const float (*hb)[NHID],
                                       half_t* Zf, int tid) {
    for (int idx = tid; idx < NN * 16; idx += 512) {
        int n = idx >> 4, c8 = idx & 15;
        int c = c8 * 8;
        const float* src = (c < NHID) ? &ha[n][c] : &hb[n][c - NHID];
        f16x8 o8;
#pragma unroll
        for (int q = 0; q < 8; ++q) o8[q] = (half_t)src[q];
        *(f16x8*)(Zf + ((c8 >> 2) * 2 + (n >> 4)) * 512 +
                  (((c8 & 3) << 4) | (n & 15)) * 8) = o8;
    }
}

// ---------------------------------------------------------------------------
// Weight pack: W[(m*C + c)][o] fp32 -> MM1 B-frag order fp16.
// ---------------------------------------------------------------------------
__global__ void pack_w(const float* __restrict__ W, f16x8* __restrict__ out,
                       int KT, int NTW, int ncol, int C) {
    int idx = blockIdx.x * blockDim.x + threadIdx.x;
    if (idx >= KT * NTW * 64) return;
    int lane = idx & 63, f = idx >> 6;
    int kt = f / NTW, ntp = f - kt * NTW;
    int ncol16 = ncol >> 4;
    int m = ntp / ncol16, ot = ntp - m * ncol16;
    int o = ot * 16 + (lane & 15);
    f16x8 v;
#pragma unroll
    for (int jj = 0; jj < 8; ++jj) {
        int c = kt * 32 + ((lane >> 4) << 3) + jj;
        v[jj] = (half_t)W[(m * C + c) * ncol + o];
    }
    out[idx] = v;
}

// ---------------------------------------------------------------------------
// Pcat pack: A-frag order fp16 for MM2.
// ---------------------------------------------------------------------------
__global__ void pack_pcat(const float* __restrict__ sup, f16x8* __restrict__ out) {
    int tid = threadIdx.x;                 // 512 threads, 1 block
    int lane = tid & 63, fidx = tid >> 6;  // 8 frags: (kt2, mtA)
    int mtA = fidx & 1, kt2 = fidx >> 1;
    int n = mtA * 16 + (lane & 15);
    f16x8 v;
#pragma unroll 1
    for (int jj = 0; jj < 8; ++jj) {
        int k = kt2 * 32 + ((lane >> 4) << 3) + jj;
        int m = k / 24, j = k - m * 24;
        float val = 0.f;
        if (n < NN && j < NN && m < 5) {
            if (m == 0)      val = (n == j) ? 1.f : 0.f;
            else if (m == 1) val = sup[0 * 324 + n * 18 + j];
            else if (m == 3) val = sup[1 * 324 + n * 18 + j];
            else {
                const float* S = sup + ((m == 2) ? 0 : 1) * 324;
                float acc = 0.f;
                for (int l = 0; l < NN; ++l) acc += S[n * 18 + l] * S[l * 18 + j];
                val = 2.f * acc - ((n == j) ? 1.f : 0.f);
            }
        }
        v[jj] = (half_t)val;
    }
    out[fidx * 64 + lane] = v;
}

// ---------------------------------------------------------------------------
// Persistent per-batch kernel: 512 blocks x 512 threads (8 waves).
// LDS: Zf 8K + Yf 32K + Pc 8K + h_a/h_b/ubuf 13.5K = 62.9K -> 2 blocks/CU.
// Per-phase: issue NEXT phase's weight-column loads, then lgkm-only barrier
// so they stay in flight (each mm1 entry finds its first columns resident).
// ---------------------------------------------------------------------------
__global__ __launch_bounds__(512, 4) void dcrnn_kernel(
    const float* __restrict__ x,
    const f16x8* __restrict__ wg0, const float* __restrict__ bg0,
    const f16x8* __restrict__ wc0, const float* __restrict__ bc0,
    const f16x8* __restrict__ wg1, const float* __restrict__ bg1,
    const f16x8* __restrict__ wc1, const float* __restrict__ bc1,
    const f16x8* __restrict__ Pf,
    const float* __restrict__ fcw, const float* __restrict__ fcb,
    float* __restrict__ out) {
    __shared__ __align__(16) half_t Zf[8 * 512];    // Z as A-frags (kt*2+mt)
    __shared__ __align__(16) half_t Yf[32 * 512];   // Ycat as B-frags (kt2*8+ot)
    __shared__ __align__(16) half_t Pc[8 * 512];    // Pcat as A-frags
    __shared__ float h_a[NN][NHID];
    __shared__ float h_b[NN][NHID];
    __shared__ float ubuf[NN][NHID];

    const int tid  = threadIdx.x;
    const int lane = tid & 63;
    const int wv   = tid >> 6;
    const int b    = blockIdx.x;

    // one-time init: zero Z/Y frag pads (pad stays zero forever), load Pcat, zero h
    {
        f16x8 z = {0, 0, 0, 0, 0, 0, 0, 0};
        ((f16x8*)Zf)[tid] = z;
#pragma unroll
        for (int i = 0; i < 4; ++i) ((f16x8*)Yf)[tid + i * 512] = z;
        ((f16x8*)Pc)[tid] = Pf[tid];
        for (int i = tid; i < NN * NHID; i += 512) {
            ((float*)h_a)[i] = 0.f;
            ((float*)h_b)[i] = 0.f;
        }
    }

    // mm1 wave partitions: gate NTW=40 -> 5/wave; cand NTW=20 -> 3,3,3,3,2,2,2,2
    const int gnt0 = wv * 5;
    const int cnt0 = (wv < 4) ? wv * 3 : 12 + (wv - 4) * 2;
    const int ccnt = (wv < 4) ? 3 : 2;
    const int ln   = lane & 15;

    const float bgt0 = bg0[wv * 16 + ln];
    const float bct0 = bc0[(wv & 3) * 16 + ln];
    const float bgt1 = bg1[wv * 16 + ln];
    const float bct1 = bc1[(wv & 3) * 16 + ln];

    __syncthreads();

    const float* xb = x + (size_t)b * NT * NN * NDIM;

    BPre<3, 3> pg0;  // gate L0: prefetch 3 of 5 cols
    BPre<4, 2> pg1;  // gate L1: prefetch 2 of 5 cols
    BPre<3, 3> pc0;  // cand L0: all (<=3) cols
    BPre<4, 3> pc1;  // cand L1: all (<=3) cols

    // prologue: stage t=0 + prefetch gate L0
    stage0(xb, h_a, Zf, tid);
    mm1_pre(pg0, wg0, 40, gnt0, 5, lane);
    BAR_LGKM();

    for (int t = 0; t < NT; ++t) {
        // ======== layer 0 ========
        mm1_main<3, 3, 5, 3>(pg0, wg0, 40, Zf, Yf, gnt0, lane);   // P1: gate mm1
        BAR_LGKM();
        mm1_pre(pc0, wc0, 20, cnt0, ccnt, lane);                  // P2: pre cand L0
        mm2_gate(Pc, Yf, Zf, bgt0, h_a, ubuf, 32, wv, lane);
        BAR_LGKM();
        if (wv < 4) mm1_main<3, 2, 3, 3>(pc0, wc0, 20, Zf, Yf, cnt0, lane);  // P3
        else        mm1_main<3, 2, 2, 3>(pc0, wc0, 20, Zf, Yf, cnt0, lane);
        BAR_LGKM();
        mm1_pre(pg1, wg1, 40, gnt0, 5, lane);                     // P4: pre gate L1
        mm2_cand(Pc, Yf, bct0, h_a, ubuf, wv, lane);
        BAR_LGKM();
        stage1(h_a, h_b, Zf, tid);                                // P5
        BAR_LGKM();

        // ======== layer 1 ========
        mm1_main<4, 3, 5, 2>(pg1, wg1, 40, Zf, Yf, gnt0, lane);   // P6: gate mm1
        BAR_LGKM();
        mm1_pre(pc1, wc1, 20, cnt0, ccnt, lane);                  // P7: pre cand L1
        mm2_gate(Pc, Yf, Zf, bgt1, h_b, ubuf, 64, wv, lane);
        BAR_LGKM();
        if (wv < 4) mm1_main<4, 2, 3, 3>(pc1, wc1, 20, Zf, Yf, cnt0, lane);  // P8
        else        mm1_main<4, 2, 2, 3>(pc1, wc1, 20, Zf, Yf, cnt0, lane);
        BAR_LGKM();
        mm1_pre(pg0, wg0, 40, gnt0, 5, lane);                     // P9: pre gate L0 (t+1)
        mm2_cand(Pc, Yf, bct1, h_b, ubuf, wv, lane);
        if (t + 1 < NT) stage0(xb + (size_t)(t + 1) * NN * NDIM, h_a, Zf, tid);
        BAR_LGKM();
    }

    __syncthreads();

    // ---- output head: out[b] = max_n (relu(h_b[n]) . fcw + fcb) ----
    if (tid < NN) {
        float acc = fcb[0];
#pragma unroll 1
        for (int c = 0; c < NHID; ++c)
            acc = fmaf(fmaxf(h_b[tid][c], 0.f), fcw[c], acc);
        ((float*)ubuf)[tid] = acc;
    }
    __syncthreads();
    if (tid == 0) {
        float m = -1e30f;
#pragma unroll
        for (int n = 0; n < NN; ++n) m = fmaxf(m, ((float*)ubuf)[n]);
        out[b] = m;
    }
}

extern "C" void kernel_launch(void* const* d_in, const int* in_sizes, int n_in,
                              void* d_out, int out_size, void* d_ws, size_t ws_size,
                              hipStream_t stream) {
    const float* x   = (const float*)d_in[0];
    const float* sup = (const float*)d_in[1];
    const float* wg0 = (const float*)d_in[2];
    const float* bg0 = (const float*)d_in[3];
    const float* wc0 = (const float*)d_in[4];
    const float* bc0 = (const float*)d_in[5];
    const float* wg1 = (const float*)d_in[6];
    const float* bg1 = (const float*)d_in[7];
    const float* wc1 = (const float*)d_in[8];
    const float* bc1 = (const float*)d_in[9];
    const float* fcw = (const float*)d_in[10];
    const float* fcb = (const float*)d_in[11];
    float* out = (float*)d_out;

    // ws: packed fp16 MM1 B-frags + Pcat A-frags (438272 B total)
    char* ws = (char*)d_ws;
    f16x8* wg0p = (f16x8*)(ws + 0);        // KT=3, NTW=40 -> 122880 B
    f16x8* wc0p = (f16x8*)(ws + 122880);   // KT=3, NTW=20 ->  61440 B
    f16x8* wg1p = (f16x8*)(ws + 184320);   // KT=4, NTW=40 -> 163840 B
    f16x8* wc1p = (f16x8*)(ws + 348160);   // KT=4, NTW=20 ->  81920 B
    f16x8* pfp  = (f16x8*)(ws + 430080);   // 8 frags      ->   8192 B

    pack_w<<<dim3(30), dim3(256), 0, stream>>>(wg0, wg0p, 3, 40, 128, 96);
    pack_w<<<dim3(15), dim3(256), 0, stream>>>(wc0, wc0p, 3, 20, 64, 96);
    pack_w<<<dim3(40), dim3(256), 0, stream>>>(wg1, wg1p, 4, 40, 128, 128);
    pack_w<<<dim3(20), dim3(256), 0, stream>>>(wc1, wc1p, 4, 20, 64, 128);
    pack_pcat<<<dim3(1), dim3(512), 0, stream>>>(sup, pfp);

    dcrnn_kernel<<<dim3(NB), dim3(512), 0, stream>>>(
        x, wg0p, bg0, wc0p, bc0, wg1p, bg1, wc1p, bc1, pfp, fcw, fcb, out);
}

// Round 3
// 3646.658 us; speedup vs baseline: 1.5094x; 1.1857x over previous
//
#include <hip/hip_runtime.h>
#include <math.h>

#define NB 512
#define NT 128
#define NN 18
#define NDIM 32
#define NHID 64

typedef _Float16 half_t;
typedef _Float16 f16x4 __attribute__((ext_vector_type(4)));
typedef _Float16 f16x8 __attribute__((ext_vector_type(8)));
typedef float    f32x4 __attribute__((ext_vector_type(4)));

__device__ __forceinline__ float fast_sigmoid(float x) {
    return __builtin_amdgcn_rcpf(1.f + __expf(-x));
}
__device__ __forceinline__ float fast_tanh(float x) {
    float xc = fminf(fmaxf(x, -15.f), 15.f);
    float e  = __expf(2.f * xc);
    return 1.f - 2.f * __builtin_amdgcn_rcpf(e + 1.f);
}
__device__ __forceinline__ f32x4 mfma16(f16x8 a, f16x8 b, f32x4 c) {
    return __builtin_amdgcn_mfma_f32_16x16x32_f16(a, b, c, 0, 0, 0);
}

// ---------------------------------------------------------------------------
// MM1: Y(18 x 5*ncol) = Z(18 x C) * W'(C x 5*ncol). Round-0 proven version:
// #pragma unroll 1 loop with rolling depth-2 B prefetch, nothing lives across
// barriers (VGPR=64 schedulable; lesson from rounds 1-2: deeper/persistent
// register prefetch spills on this geometry).
// SCATTER RULE (race fix): mt=0 writes rows 0..15 (all quads); mt=1 writes
// ONLY quad==0 (rows 16..19). Rows 20..23 / 120..127 stay zero from init.
// ---------------------------------------------------------------------------
template <int KT>
__device__ __forceinline__ void mm1(const f16x8* __restrict__ Wf, int NTW, int ncs,
                                    const half_t* Zf, half_t* Yf,
                                    int nt0, int cnt, int lane) {
    f16x8 A[2 * KT];
#pragma unroll
    for (int kt = 0; kt < KT; ++kt) {
        A[kt * 2 + 0] = *(const f16x8*)(Zf + (kt * 2 + 0) * 512 + lane * 8);
        A[kt * 2 + 1] = *(const f16x8*)(Zf + (kt * 2 + 1) * 512 + lane * 8);
    }
    f16x8 B0[KT], B1[KT];
#pragma unroll
    for (int kt = 0; kt < KT; ++kt) B0[kt] = Wf[(kt * NTW + nt0) * 64 + lane];
    if (cnt > 1) {
#pragma unroll
        for (int kt = 0; kt < KT; ++kt) B1[kt] = Wf[(kt * NTW + nt0 + 1) * 64 + lane];
    }
    const int quad = lane >> 4, ln = lane & 15;
#pragma unroll 1
    for (int i = 0; i < cnt; ++i) {
        const int ntp = nt0 + i;
        f16x8 Bc[KT];
#pragma unroll
        for (int kt = 0; kt < KT; ++kt) { Bc[kt] = B0[kt]; B0[kt] = B1[kt]; }
        if (i + 2 < cnt) {
#pragma unroll
            for (int kt = 0; kt < KT; ++kt) B1[kt] = Wf[(kt * NTW + ntp + 2) * 64 + lane];
        }
        f32x4 ac0 = {0.f, 0.f, 0.f, 0.f};
        f32x4 ac1 = {0.f, 0.f, 0.f, 0.f};
#pragma unroll
        for (int kt = 0; kt < KT; ++kt) {
            ac0 = mfma16(A[kt * 2 + 0], Bc[kt], ac0);
            ac1 = mfma16(A[kt * 2 + 1], Bc[kt], ac1);
        }
        const int m  = ntp >> ncs;            // ncol16 = 1<<ncs
        const int ot = ntp - (m << ncs);
        // mt=0: rows k = 24m + quad*4 + r (0..15)
        {
            const int k0 = 24 * m + quad * 4;
            f16x4 pk;
#pragma unroll
            for (int r = 0; r < 4; ++r) pk[r] = (half_t)ac0[r];
            *(f16x4*)(Yf + ((k0 >> 5) * 8 + ot) * 512 +
                      (((((k0 >> 3) & 3) << 4) | ln) * 8) + (k0 & 7)) = pk;
        }
        // mt=1: only quad 0 -> rows 16..19 (16,17 real; 18,19 zero)
        if (quad == 0) {
            const int k0 = 24 * m + 16;       // multiple of 8
            f16x4 pk;
#pragma unroll
            for (int r = 0; r < 4; ++r) pk[r] = (half_t)ac1[r];
            *(f16x4*)(Yf + ((k0 >> 5) * 8 + ot) * 512 +
                      (((((k0 >> 3) & 3) << 4) | ln) * 8) + (k0 & 7)) = pk;
        }
    }
}

// ---------------------------------------------------------------------------
// MM2 gate: ru(18 x 128) = Pcat(18 x 120pad128) * Ycat + bias -> sigmoid.
// o<64: r -> write r*h into Z frags (kZ = DIMin+o); o>=64: u -> ubuf.
// ---------------------------------------------------------------------------
__device__ __forceinline__ void mm2_gate(const half_t* Pc, const half_t* Yf,
                                         half_t* Zf, float bias,
                                         const float (*h)[NHID], float (*ub)[NHID],
                                         int DIMin, int wv, int lane) {
    const int nt2 = wv, quad = lane >> 4, ln = lane & 15;
    f32x4 a0 = {0.f, 0.f, 0.f, 0.f};
    f32x4 a1 = {0.f, 0.f, 0.f, 0.f};
#pragma unroll
    for (int kt = 0; kt < 4; ++kt) {
        f16x8 B  = *(const f16x8*)(Yf + (kt * 8 + nt2) * 512 + lane * 8);
        f16x8 A0 = *(const f16x8*)(Pc + (kt * 2 + 0) * 512 + lane * 8);
        f16x8 A1 = *(const f16x8*)(Pc + (kt * 2 + 1) * 512 + lane * 8);
        a0 = mfma16(A0, B, a0);
        a1 = mfma16(A1, B, a1);
    }
    const int o = nt2 * 16 + ln;
    if (o < NHID) {
        const int kZ = DIMin + o;
        const int base = ((kZ >> 5) * 2) * 512 + (((kZ >> 3) & 3) << 4) * 8 + (kZ & 7);
#pragma unroll
        for (int r = 0; r < 4; ++r) {
            int n = quad * 4 + r;
            float rv = fast_sigmoid(a0[r] + bias);
            Zf[base + (n & 15) * 8] = (half_t)(rv * h[n][o]);
        }
        if (quad == 0) {
#pragma unroll
            for (int r = 0; r < 2; ++r) {
                int n = 16 + r;
                float rv = fast_sigmoid(a1[r] + bias);
                Zf[base + 512 + (n & 15) * 8] = (half_t)(rv * h[n][o]);
            }
        }
    } else {
        const int oc = o - NHID;
#pragma unroll
        for (int r = 0; r < 4; ++r) ub[quad * 4 + r][oc] = fast_sigmoid(a0[r] + bias);
        if (quad == 0) {
#pragma unroll
            for (int r = 0; r < 2; ++r) ub[16 + r][oc] = fast_sigmoid(a1[r] + bias);
        }
    }
}

// ---------------------------------------------------------------------------
// MM2 cand FUSED: c = tanh(Pcat*Ycat + bias); h = u*h + (1-u)*c.
// Writes h back as f32 (recurrence, full precision) AND as f16 frags directly
// into the next consumers' Z buffers (replaces the old stage0/stage1 passes;
// identical RTE rounding). NTGT=2: write Zt0[ra+off0] and Zt1[ra+off1];
// NTGT=1: Zt0 only. ra = frag address for (row n, col kZ=o); +1024 shifts
// kZ by +32, +2048 by +64 (verified: low bits of kZ unchanged mod 32).
// ---------------------------------------------------------------------------
template <int NTGT>
__device__ __forceinline__ void mm2_cand_f(const half_t* Pc, const half_t* Yf,
                                           float bias, float (*h)[NHID],
                                           const float (*ub)[NHID],
                                           half_t* Zt0, int off0,
                                           half_t* Zt1, int off1,
                                           int wv, int lane) {
    const int nt2 = wv & 3, mtA = wv >> 2;
    const int quad = lane >> 4, ln = lane & 15;
    f32x4 a = {0.f, 0.f, 0.f, 0.f};
#pragma unroll
    for (int kt = 0; kt < 4; ++kt) {
        f16x8 B = *(const f16x8*)(Yf + (kt * 8 + nt2) * 512 + lane * 8);
        f16x8 A = *(const f16x8*)(Pc + (kt * 2 + mtA) * 512 + lane * 8);
        a = mfma16(A, B, a);
    }
    const int o = nt2 * 16 + ln;
    const int baseL = ((o >> 5) * 2) * 512 + (((o >> 3) & 3) << 4) * 8 + (o & 7);
#pragma unroll
    for (int r = 0; r < 4; ++r) {
        int n = mtA * 16 + quad * 4 + r;
        if (n < NN) {
            float cv = fast_tanh(a[r] + bias);
            float uv = ub[n][o];
            float hn = uv * h[n][o] + (1.f - uv) * cv;
            h[n][o] = hn;
            half_t hh = (half_t)hn;
            const int ra = baseL + (n & 15) * 8 + (n >> 4) * 512;
            Zt0[ra + off0] = hh;
            if (NTGT == 2) Zt1[ra + off1] = hh;
        }
    }
}

// x-only stage: Zf0 left half (kZ = 0..31) <- x(t). 72 threads, 2 float4 each.
__device__ __forceinline__ void stage_x(const float* __restrict__ xt,
                                        half_t* Zf0, int tid) {
    if (tid < NN * 4) {
        int n = tid >> 2, c8 = tid & 3;
        const float* src = xt + n * NDIM + c8 * 8;
        f16x8 o8;
#pragma unroll
        for (int q = 0; q < 8; ++q) o8[q] = (half_t)src[q];
        *(f16x8*)(Zf0 + (n >> 4) * 512 + (((c8 & 3) << 4) | (n & 15)) * 8) = o8;
    }
}

// ---------------------------------------------------------------------------
// Weight pack: W[(m*C + c)][o] fp32 -> MM1 B-frag order fp16.
// ---------------------------------------------------------------------------
__global__ void pack_w(const float* __restrict__ W, f16x8* __restrict__ out,
                       int KT, int NTW, int ncol, int C) {
    int idx = blockIdx.x * blockDim.x + threadIdx.x;
    if (idx >= KT * NTW * 64) return;
    int lane = idx & 63, f = idx >> 6;
    int kt = f / NTW, ntp = f - kt * NTW;
    int ncol16 = ncol >> 4;
    int m = ntp / ncol16, ot = ntp - m * ncol16;
    int o = ot * 16 + (lane & 15);
    f16x8 v;
#pragma unroll
    for (int jj = 0; jj < 8; ++jj) {
        int c = kt * 32 + ((lane >> 4) << 3) + jj;
        v[jj] = (half_t)W[(m * C + c) * ncol + o];
    }
    out[idx] = v;
}

// ---------------------------------------------------------------------------
// Pcat pack: A-frag order fp16 for MM2.
// ---------------------------------------------------------------------------
__global__ void pack_pcat(const float* __restrict__ sup, f16x8* __restrict__ out) {
    int tid = threadIdx.x;                 // 512 threads, 1 block
    int lane = tid & 63, fidx = tid >> 6;  // 8 frags: (kt2, mtA)
    int mtA = fidx & 1, kt2 = fidx >> 1;
    int n = mtA * 16 + (lane & 15);
    f16x8 v;
#pragma unroll 1
    for (int jj = 0; jj < 8; ++jj) {
        int k = kt2 * 32 + ((lane >> 4) << 3) + jj;
        int m = k / 24, j = k - m * 24;
        float val = 0.f;
        if (n < NN && j < NN && m < 5) {
            if (m == 0)      val = (n == j) ? 1.f : 0.f;
            else if (m == 1) val = sup[0 * 324 + n * 18 + j];
            else if (m == 3) val = sup[1 * 324 + n * 18 + j];
            else {
                const float* S = sup + ((m == 2) ? 0 : 1) * 324;
                float acc = 0.f;
                for (int l = 0; l < NN; ++l) acc += S[n * 18 + l] * S[l * 18 + j];
                val = 2.f * acc - ((n == j) ? 1.f : 0.f);
            }
        }
        v[jj] = (half_t)val;
    }
    out[fidx * 64 + lane] = v;
}

// ---------------------------------------------------------------------------
// Persistent per-batch kernel: 512 blocks x 512 threads (8 waves).
// LDS: Zf0 6K + Zf1 8K + Yf 32K + Pc 8K + h/ubuf 13.5K = 67.6K -> 2 blocks/CU.
// 8 barriers/step (was 10): stage passes fused into mm2_cand frag writes.
// ---------------------------------------------------------------------------
__global__ __launch_bounds__(512, 4) void dcrnn_kernel(
    const float* __restrict__ x,
    const f16x8* __restrict__ wg0, const float* __restrict__ bg0,
    const f16x8* __restrict__ wc0, const float* __restrict__ bc0,
    const f16x8* __restrict__ wg1, const float* __restrict__ bg1,
    const f16x8* __restrict__ wc1, const float* __restrict__ bc1,
    const f16x8* __restrict__ Pf,
    const float* __restrict__ fcw, const float* __restrict__ fcb,
    float* __restrict__ out) {
    __shared__ __align__(16) half_t Zf0[6 * 512];   // L0 Z: [x | h_a] A-frags
    __shared__ __align__(16) half_t Zf1[8 * 512];   // L1 Z: [h_a | h_b] A-frags
    __shared__ __align__(16) half_t Yf[32 * 512];   // Ycat as B-frags (kt2*8+ot)
    __shared__ __align__(16) half_t Pc[8 * 512];    // Pcat as A-frags
    __shared__ float h_a[NN][NHID];
    __shared__ float h_b[NN][NHID];
    __shared__ float ubuf[NN][NHID];

    const int tid  = threadIdx.x;
    const int lane = tid & 63;
    const int wv   = tid >> 6;
    const int b    = blockIdx.x;

    // one-time init: zero all frag buffers (pads stay zero forever), load Pcat, zero h
    {
        f16x8 z = {0, 0, 0, 0, 0, 0, 0, 0};
        if (tid < 384) ((f16x8*)Zf0)[tid] = z;
        ((f16x8*)Zf1)[tid] = z;
#pragma unroll
        for (int i = 0; i < 4; ++i) ((f16x8*)Yf)[tid + i * 512] = z;
        ((f16x8*)Pc)[tid] = Pf[tid];
        for (int i = tid; i < NN * NHID; i += 512) {
            ((float*)h_a)[i] = 0.f;
            ((float*)h_b)[i] = 0.f;
        }
    }

    // mm1 wave partitions: gate NTW=40 -> 5/wave; cand NTW=20 -> 3,3,3,3,2,2,2,2
    const int gnt0 = wv * 5;
    const int cnt0 = (wv < 4) ? wv * 3 : 12 + (wv - 4) * 2;
    const int ccnt = (wv < 4) ? 3 : 2;
    const int ln   = lane & 15;

    const float bgt0 = bg0[wv * 16 + ln];
    const float bct0 = bc0[(wv & 3) * 16 + ln];
    const float bgt1 = bg1[wv * 16 + ln];
    const float bct1 = bc1[(wv & 3) * 16 + ln];

    const float* xb = x + (size_t)b * NT * NN * NDIM;

    // prologue: x(0) into Zf0 left (h regions are zero = initial state)
    stage_x(xb, Zf0, tid);
    __syncthreads();

    for (int t = 0; t < NT; ++t) {
        // ======== layer 0: C=96 (KT=3) ========
        mm1<3>(wg0, 40, 3, Zf0, Yf, gnt0, 5, lane);                 // P1 gate mm1
        __syncthreads();
        mm2_gate(Pc, Yf, Zf0, bgt0, h_a, ubuf, 32, wv, lane);       // P2 -> r*h in Zf0
        __syncthreads();
        mm1<3>(wc0, 20, 2, Zf0, Yf, cnt0, ccnt, lane);              // P3 cand mm1
        __syncthreads();
        // P4: x(t+1) -> Zf0 left; h_a update -> f32 + Zf1 left + Zf0 right
        if (t + 1 < NT) stage_x(xb + (size_t)(t + 1) * NN * NDIM, Zf0, tid);
        mm2_cand_f<2>(Pc, Yf, bct0, h_a, ubuf, Zf1, 0, Zf0, 1024, wv, lane);
        __syncthreads();

        // ======== layer 1: C=128 (KT=4) ========
        mm1<4>(wg1, 40, 3, Zf1, Yf, gnt0, 5, lane);                 // P5 gate mm1
        __syncthreads();
        mm2_gate(Pc, Yf, Zf1, bgt1, h_b, ubuf, 64, wv, lane);       // P6 -> r*h in Zf1
        __syncthreads();
        mm1<4>(wc1, 20, 2, Zf1, Yf, cnt0, ccnt, lane);              // P7 cand mm1
        __syncthreads();
        // P8: h_b update -> f32 + Zf1 right (next step's gate input)
        mm2_cand_f<1>(Pc, Yf, bct1, h_b, ubuf, Zf1, 2048, Zf1, 0, wv, lane);
        __syncthreads();
    }

    // ---- output head: out[b] = max_n (relu(h_b[n]) . fcw + fcb) ----
    if (tid < NN) {
        float acc = fcb[0];
#pragma unroll 1
        for (int c = 0; c < NHID; ++c)
            acc = fmaf(fmaxf(h_b[tid][c], 0.f), fcw[c], acc);
        ((float*)ubuf)[tid] = acc;
    }
    __syncthreads();
    if (tid == 0) {
        float m = -1e30f;
#pragma unroll
        for (int n = 0; n < NN; ++n) m = fmaxf(m, ((float*)ubuf)[n]);
        out[b] = m;
    }
}

extern "C" void kernel_launch(void* const* d_in, const int* in_sizes, int n_in,
                              void* d_out, int out_size, void* d_ws, size_t ws_size,
                              hipStream_t stream) {
    const float* x   = (const float*)d_in[0];
    const float* sup = (const float*)d_in[1];
    const float* wg0 = (const float*)d_in[2];
    const float* bg0 = (const float*)d_in[3];
    const float* wc0 = (const float*)d_in[4];
    const float* bc0 = (const float*)d_in[5];
    const float* wg1 = (const float*)d_in[6];
    const float* bg1 = (const float*)d_in[7];
    const float* wc1 = (const float*)d_in[8];
    const float* bc1 = (const float*)d_in[9];
    const float* fcw = (const float*)d_in[10];
    const float* fcb = (const float*)d_in[11];
    float* out = (float*)d_out;

    // ws: packed fp16 MM1 B-frags + Pcat A-frags (438272 B total)
    char* ws = (char*)d_ws;
    f16x8* wg0p = (f16x8*)(ws + 0);        // KT=3, NTW=40 -> 122880 B
    f16x8* wc0p = (f16x8*)(ws + 122880);   // KT=3, NTW=20 ->  61440 B
    f16x8* wg1p = (f16x8*)(ws + 184320);   // KT=4, NTW=40 -> 163840 B
    f16x8* wc1p = (f16x8*)(ws + 348160);   // KT=4, NTW=20 ->  81920 B
    f16x8* pfp  = (f16x8*)(ws + 430080);   // 8 frags      ->   8192 B

    pack_w<<<dim3(30), dim3(256), 0, stream>>>(wg0, wg0p, 3, 40, 128, 96);
    pack_w<<<dim3(15), dim3(256), 0, stream>>>(wc0, wc0p, 3, 20, 64, 96);
    pack_w<<<dim3(40), dim3(256), 0, stream>>>(wg1, wg1p, 4, 40, 128, 128);
    pack_w<<<dim3(20), dim3(256), 0, stream>>>(wc1, wc1p, 4, 20, 64, 128);
    pack_pcat<<<dim3(1), dim3(512), 0, stream>>>(sup, pfp);

    dcrnn_kernel<<<dim3(NB), dim3(512), 0, stream>>>(
        x, wg0p, bg0, wc0p, bc0, wg1p, bg1, wc1p, bc1, pfp, fcw, fcb, out);
}

// Round 4
// 3640.266 us; speedup vs baseline: 1.5121x; 1.0018x over previous
//
#include <hip/hip_runtime.h>
#include <math.h>

#define NB 512
#define NBLK 256   // 2 batch elements per block
#define NT 128
#define NN 18
#define NDIM 32
#define NHID 64

typedef _Float16 half_t;
typedef _Float16 f16x4 __attribute__((ext_vector_type(4)));
typedef _Float16 f16x8 __attribute__((ext_vector_type(8)));
typedef float    f32x4 __attribute__((ext_vector_type(4)));

__device__ __forceinline__ float fast_sigmoid(float x) {
    return __builtin_amdgcn_rcpf(1.f + __expf(-x));
}
__device__ __forceinline__ float fast_tanh(float x) {
    float xc = fminf(fmaxf(x, -15.f), 15.f);
    float e  = __expf(2.f * xc);
    return 1.f - 2.f * __builtin_amdgcn_rcpf(e + 1.f);
}
__device__ __forceinline__ f32x4 mfma16(f16x8 a, f16x8 b, f32x4 c) {
    return __builtin_amdgcn_mfma_f32_16x16x32_f16(a, b, c, 0, 0, 0);
}

// ---------------------------------------------------------------------------
// MM1: Y(18 x 5*ncol) = Z(18 x C) * W'(C x 5*ncol). Round-0 proven version:
// #pragma unroll 1 loop with rolling depth-2 B prefetch; nothing lives across
// barriers (rounds 1-2 lesson: cross-barrier register residency spills at the
// 128-VGPR occupancy cap).
// SCATTER RULE (race fix): mt=0 writes rows 0..15 (all quads); mt=1 writes
// ONLY quad==0 (rows 16..19). Rows 20..23 / 120..127 stay zero from init.
// ---------------------------------------------------------------------------
template <int KT>
__device__ __forceinline__ void mm1(const f16x8* __restrict__ Wf, int NTW, int ncs,
                                    const half_t* Zf, half_t* Yf,
                                    int nt0, int cnt, int lane) {
    f16x8 A[2 * KT];
#pragma unroll
    for (int kt = 0; kt < KT; ++kt) {
        A[kt * 2 + 0] = *(const f16x8*)(Zf + (kt * 2 + 0) * 512 + lane * 8);
        A[kt * 2 + 1] = *(const f16x8*)(Zf + (kt * 2 + 1) * 512 + lane * 8);
    }
    f16x8 B0[KT], B1[KT];
#pragma unroll
    for (int kt = 0; kt < KT; ++kt) B0[kt] = Wf[(kt * NTW + nt0) * 64 + lane];
    if (cnt > 1) {
#pragma unroll
        for (int kt = 0; kt < KT; ++kt) B1[kt] = Wf[(kt * NTW + nt0 + 1) * 64 + lane];
    }
    const int quad = lane >> 4, ln = lane & 15;
#pragma unroll 1
    for (int i = 0; i < cnt; ++i) {
        const int ntp = nt0 + i;
        f16x8 Bc[KT];
#pragma unroll
        for (int kt = 0; kt < KT; ++kt) { Bc[kt] = B0[kt]; B0[kt] = B1[kt]; }
        if (i + 2 < cnt) {
#pragma unroll
            for (int kt = 0; kt < KT; ++kt) B1[kt] = Wf[(kt * NTW + ntp + 2) * 64 + lane];
        }
        f32x4 ac0 = {0.f, 0.f, 0.f, 0.f};
        f32x4 ac1 = {0.f, 0.f, 0.f, 0.f};
#pragma unroll
        for (int kt = 0; kt < KT; ++kt) {
            ac0 = mfma16(A[kt * 2 + 0], Bc[kt], ac0);
            ac1 = mfma16(A[kt * 2 + 1], Bc[kt], ac1);
        }
        const int m  = ntp >> ncs;            // ncol16 = 1<<ncs
        const int ot = ntp - (m << ncs);
        // mt=0: rows k = 24m + quad*4 + r (0..15)
        {
            const int k0 = 24 * m + quad * 4;
            f16x4 pk;
#pragma unroll
            for (int r = 0; r < 4; ++r) pk[r] = (half_t)ac0[r];
            *(f16x4*)(Yf + ((k0 >> 5) * 8 + ot) * 512 +
                      (((((k0 >> 3) & 3) << 4) | ln) * 8) + (k0 & 7)) = pk;
        }
        // mt=1: only quad 0 -> rows 16..19 (16,17 real; 18,19 zero)
        if (quad == 0) {
            const int k0 = 24 * m + 16;       // multiple of 8
            f16x4 pk;
#pragma unroll
            for (int r = 0; r < 4; ++r) pk[r] = (half_t)ac1[r];
            *(f16x4*)(Yf + ((k0 >> 5) * 8 + ot) * 512 +
                      (((((k0 >> 3) & 3) << 4) | ln) * 8) + (k0 & 7)) = pk;
        }
    }
}

// ---------------------------------------------------------------------------
// MM2 gate: ru(18 x 128) = Pcat(18 x 120pad128) * Ycat + bias -> sigmoid.
// w8 = wave sub-index (0..7) within the elem. o<64: r -> write r*h into Z
// frags (kZ = DIMin+o); o>=64: u -> ubuf. Does NOT read Zf.
// ---------------------------------------------------------------------------
__device__ __forceinline__ void mm2_gate(const half_t* Pc, const half_t* Yf,
                                         half_t* Zf, float bias,
                                         const float (*h)[NHID], float (*ub)[NHID],
                                         int DIMin, int w8, int lane) {
    const int nt2 = w8, quad = lane >> 4, ln = lane & 15;
    f32x4 a0 = {0.f, 0.f, 0.f, 0.f};
    f32x4 a1 = {0.f, 0.f, 0.f, 0.f};
#pragma unroll
    for (int kt = 0; kt < 4; ++kt) {
        f16x8 B  = *(const f16x8*)(Yf + (kt * 8 + nt2) * 512 + lane * 8);
        f16x8 A0 = *(const f16x8*)(Pc + (kt * 2 + 0) * 512 + lane * 8);
        f16x8 A1 = *(const f16x8*)(Pc + (kt * 2 + 1) * 512 + lane * 8);
        a0 = mfma16(A0, B, a0);
        a1 = mfma16(A1, B, a1);
    }
    const int o = nt2 * 16 + ln;
    if (o < NHID) {
        const int kZ = DIMin + o;
        const int base = ((kZ >> 5) * 2) * 512 + (((kZ >> 3) & 3) << 4) * 8 + (kZ & 7);
#pragma unroll
        for (int r = 0; r < 4; ++r) {
            int n = quad * 4 + r;
            float rv = fast_sigmoid(a0[r] + bias);
            Zf[base + (n & 15) * 8] = (half_t)(rv * h[n][o]);
        }
        if (quad == 0) {
#pragma unroll
            for (int r = 0; r < 2; ++r) {
                int n = 16 + r;
                float rv = fast_sigmoid(a1[r] + bias);
                Zf[base + 512 + (n & 15) * 8] = (half_t)(rv * h[n][o]);
            }
        }
    } else {
        const int oc = o - NHID;
#pragma unroll
        for (int r = 0; r < 4; ++r) ub[quad * 4 + r][oc] = fast_sigmoid(a0[r] + bias);
        if (quad == 0) {
#pragma unroll
            for (int r = 0; r < 2; ++r) ub[16 + r][oc] = fast_sigmoid(a1[r] + bias);
        }
    }
}

// ---------------------------------------------------------------------------
// MM2 cand: c = tanh(Pcat * Ycat + bias); h = u*h + (1-u)*c.
// w8: nt2 = w8&3, mtA = w8>>2.
// ---------------------------------------------------------------------------
__device__ __forceinline__ void mm2_cand(const half_t* Pc, const half_t* Yf,
                                         float bias, float (*h)[NHID],
                                         const float (*ub)[NHID], int w8, int lane) {
    const int nt2 = w8 & 3, mtA = w8 >> 2;
    const int quad = lane >> 4;
    f32x4 a = {0.f, 0.f, 0.f, 0.f};
#pragma unroll
    for (int kt = 0; kt < 4; ++kt) {
        f16x8 B = *(const f16x8*)(Yf + (kt * 8 + nt2) * 512 + lane * 8);
        f16x8 A = *(const f16x8*)(Pc + (kt * 2 + mtA) * 512 + lane * 8);
        a = mfma16(A, B, a);
    }
    const int o = nt2 * 16 + (lane & 15);
#pragma unroll
    for (int r = 0; r < 4; ++r) {
        int n = mtA * 16 + quad * 4 + r;
        if (n < NN) {
            float cv = fast_tanh(a[r] + bias);
            float uv = ub[n][o];
            h[n][o] = uv * h[n][o] + (1.f - uv) * cv;
        }
    }
}

// stage A (layer 0): Zf <- [x | h_a] as A-frags; t9 = tid within elem half.
__device__ __forceinline__ void stage0(const float* __restrict__ xt,
                                       const float (*h)[NHID], half_t* Zf, int t9) {
    for (int idx = t9; idx < NN * 12; idx += 512) {
        int n = idx / 12, c8 = idx - n * 12;
        int c = c8 * 8;
        const float* src = (c < NDIM) ? &xt[n * NDIM + c] : &h[n][c - NDIM];
        f16x8 o8;
#pragma unroll
        for (int q = 0; q < 8; ++q) o8[q] = (half_t)src[q];
        *(f16x8*)(Zf + ((c8 >> 2) * 2 + (n >> 4)) * 512 +
                  (((c8 & 3) << 4) | (n & 15)) * 8) = o8;
    }
}

// stage A (layer 1): Zf <- [h_a | h_b] as A-frags
__device__ __forceinline__ void stage1(const float (*ha)[NHID], const float (*hb)[NHID],
                                       half_t* Zf, int t9) {
    for (int idx = t9; idx < NN * 16; idx += 512) {
        int n = idx >> 4, c8 = idx & 15;
        int c = c8 * 8;
        const float* src = (c < NHID) ? &ha[n][c] : &hb[n][c - NHID];
        f16x8 o8;
#pragma unroll
        for (int q = 0; q < 8; ++q) o8[q] = (half_t)src[q];
        *(f16x8*)(Zf + ((c8 >> 2) * 2 + (n >> 4)) * 512 +
                  (((c8 & 3) << 4) | (n & 15)) * 8) = o8;
    }
}

// ---------------------------------------------------------------------------
// Weight pack: W[(m*C + c)][o] fp32 -> MM1 B-frag order fp16.
// ---------------------------------------------------------------------------
__global__ void pack_w(const float* __restrict__ W, f16x8* __restrict__ out,
                       int KT, int NTW, int ncol, int C) {
    int idx = blockIdx.x * blockDim.x + threadIdx.x;
    if (idx >= KT * NTW * 64) return;
    int lane = idx & 63, f = idx >> 6;
    int kt = f / NTW, ntp = f - kt * NTW;
    int ncol16 = ncol >> 4;
    int m = ntp / ncol16, ot = ntp - m * ncol16;
    int o = ot * 16 + (lane & 15);
    f16x8 v;
#pragma unroll
    for (int jj = 0; jj < 8; ++jj) {
        int c = kt * 32 + ((lane >> 4) << 3) + jj;
        v[jj] = (half_t)W[(m * C + c) * ncol + o];
    }
    out[idx] = v;
}

// ---------------------------------------------------------------------------
// Pcat pack: A-frag order fp16 for MM2.
// ---------------------------------------------------------------------------
__global__ void pack_pcat(const float* __restrict__ sup, f16x8* __restrict__ out) {
    int tid = threadIdx.x;                 // 512 threads, 1 block
    int lane = tid & 63, fidx = tid >> 6;  // 8 frags: (kt2, mtA)
    int mtA = fidx & 1, kt2 = fidx >> 1;
    int n = mtA * 16 + (lane & 15);
    f16x8 v;
#pragma unroll 1
    for (int jj = 0; jj < 8; ++jj) {
        int k = kt2 * 32 + ((lane >> 4) << 3) + jj;
        int m = k / 24, j = k - m * 24;
        float val = 0.f;
        if (n < NN && j < NN && m < 5) {
            if (m == 0)      val = (n == j) ? 1.f : 0.f;
            else if (m == 1) val = sup[0 * 324 + n * 18 + j];
            else if (m == 3) val = sup[1 * 324 + n * 18 + j];
            else {
                const float* S = sup + ((m == 2) ? 0 : 1) * 324;
                float acc = 0.f;
                for (int l = 0; l < NN; ++l) acc += S[n * 18 + l] * S[l * 18 + j];
                val = 2.f * acc - ((n == j) ? 1.f : 0.f);
            }
        }
        v[jj] = (half_t)val;
    }
    out[fidx * 64 + lane] = v;
}

// ---------------------------------------------------------------------------
// Persistent kernel: 256 blocks x 1024 threads (16 waves), 2 batch elements
// per block. Waves 0-7 -> elem 0, waves 8-15 -> elem 1: wave w and w+8 issue
// IDENTICAL weight loads in the same phase, so each weight fetch (the
// dominant L2-miss traffic, 420 KB/step) now serves TWO batch elements, and
// each barrier serves two elements' work. Per-wave code identical to r0.
// LDS: 2*(Zf 8K + Yf 32K) + Pc 8K + 2*3*4.5K = 117.8K -> 1 block/CU,
// 16 waves/CU (same occupancy as r0's 2x8).
// ---------------------------------------------------------------------------
__global__ __launch_bounds__(1024, 4) void dcrnn_kernel(
    const float* __restrict__ x,
    const f16x8* __restrict__ wg0, const float* __restrict__ bg0,
    const f16x8* __restrict__ wc0, const float* __restrict__ bc0,
    const f16x8* __restrict__ wg1, const float* __restrict__ bg1,
    const f16x8* __restrict__ wc1, const float* __restrict__ bc1,
    const f16x8* __restrict__ Pf,
    const float* __restrict__ fcw, const float* __restrict__ fcb,
    float* __restrict__ out) {
    __shared__ __align__(16) half_t Zf[2][8 * 512];   // per-elem Z A-frags
    __shared__ __align__(16) half_t Yf[2][32 * 512];  // per-elem Ycat B-frags
    __shared__ __align__(16) half_t Pc[8 * 512];      // Pcat A-frags (shared)
    __shared__ float h_a[2][NN][NHID];
    __shared__ float h_b[2][NN][NHID];
    __shared__ float ubuf[2][NN][NHID];

    const int tid  = threadIdx.x;
    const int lane = tid & 63;
    const int wv   = tid >> 6;      // 0..15
    const int e    = wv >> 3;       // batch element within block (0/1)
    const int w8   = wv & 7;        // wave sub-index within element
    const int t9   = tid & 511;     // thread index within element half
    const int b    = blockIdx.x;

    // one-time init: zero frag pads (stay zero forever), load Pcat, zero h
    {
        f16x8 z = {0, 0, 0, 0, 0, 0, 0, 0};
        ((f16x8*)Zf[e])[t9] = z;
#pragma unroll
        for (int i = 0; i < 4; ++i) ((f16x8*)Yf[e])[t9 + i * 512] = z;
        if (tid < 512) ((f16x8*)Pc)[tid] = Pf[tid];
        for (int i = t9; i < NN * NHID; i += 512) {
            ((float*)h_a[e])[i] = 0.f;
            ((float*)h_b[e])[i] = 0.f;
        }
    }

    // mm1 wave partitions (per elem): gate NTW=40 -> 5/wave; cand NTW=20 ->
    // 3,3,3,3,2,2,2,2 across w8.
    const int gnt0 = w8 * 5;
    const int cnt0 = (w8 < 4) ? w8 * 3 : 12 + (w8 - 4) * 2;
    const int ccnt = (w8 < 4) ? 3 : 2;
    const int ln   = lane & 15;

    const float bgt0 = bg0[w8 * 16 + ln];
    const float bct0 = bc0[(w8 & 3) * 16 + ln];
    const float bgt1 = bg1[w8 * 16 + ln];
    const float bct1 = bc1[(w8 & 3) * 16 + ln];

    __syncthreads();

    const float* xb = x + (size_t)(b * 2 + e) * NT * NN * NDIM;
    half_t* Zfe = Zf[e];
    half_t* Yfe = Yf[e];

    for (int t = 0; t < NT; ++t) {
        const float* xt = xb + (size_t)t * NN * NDIM;

        // ======== layer 0: C=96 (KT=3), DIMin=32 ========
        stage0(xt, h_a[e], Zfe, t9);
        __syncthreads();
        mm1<3>(wg0, 40, 3, Zfe, Yfe, gnt0, 5, lane);
        __syncthreads();
        mm2_gate(Pc, Yfe, Zfe, bgt0, h_a[e], ubuf[e], 32, w8, lane);
        __syncthreads();
        mm1<3>(wc0, 20, 2, Zfe, Yfe, cnt0, ccnt, lane);
        __syncthreads();
        mm2_cand(Pc, Yfe, bct0, h_a[e], ubuf[e], w8, lane);
        __syncthreads();

        // ======== layer 1: C=128 (KT=4), DIMin=64 ========
        stage1(h_a[e], h_b[e], Zfe, t9);
        __syncthreads();
        mm1<4>(wg1, 40, 3, Zfe, Yfe, gnt0, 5, lane);
        __syncthreads();
        mm2_gate(Pc, Yfe, Zfe, bgt1, h_b[e], ubuf[e], 64, w8, lane);
        __syncthreads();
        mm1<4>(wc1, 20, 2, Zfe, Yfe, cnt0, ccnt, lane);
        __syncthreads();
        mm2_cand(Pc, Yfe, bct1, h_b[e], ubuf[e], w8, lane);
        __syncthreads();
    }

    // ---- output head: out[2b+e] = max_n (relu(h_b[e][n]) . fcw + fcb) ----
    if (t9 < NN) {
        float acc = fcb[0];
#pragma unroll 1
        for (int c = 0; c < NHID; ++c)
            acc = fmaf(fmaxf(h_b[e][t9][c], 0.f), fcw[c], acc);
        ((float*)ubuf[e])[t9] = acc;
    }
    __syncthreads();
    if (t9 == 0) {
        float m = -1e30f;
#pragma unroll
        for (int n = 0; n < NN; ++n) m = fmaxf(m, ((float*)ubuf[e])[n]);
        out[b * 2 + e] = m;
    }
}

extern "C" void kernel_launch(void* const* d_in, const int* in_sizes, int n_in,
                              void* d_out, int out_size, void* d_ws, size_t ws_size,
                              hipStream_t stream) {
    const float* x   = (const float*)d_in[0];
    const float* sup = (const float*)d_in[1];
    const float* wg0 = (const float*)d_in[2];
    const float* bg0 = (const float*)d_in[3];
    const float* wc0 = (const float*)d_in[4];
    const float* bc0 = (const float*)d_in[5];
    const float* wg1 = (const float*)d_in[6];
    const float* bg1 = (const float*)d_in[7];
    const float* wc1 = (const float*)d_in[8];
    const float* bc1 = (const float*)d_in[9];
    const float* fcw = (const float*)d_in[10];
    const float* fcb = (const float*)d_in[11];
    float* out = (float*)d_out;

    // ws: packed fp16 MM1 B-frags + Pcat A-frags (438272 B total)
    char* ws = (char*)d_ws;
    f16x8* wg0p = (f16x8*)(ws + 0);        // KT=3, NTW=40 -> 122880 B
    f16x8* wc0p = (f16x8*)(ws + 122880);   // KT=3, NTW=20 ->  61440 B
    f16x8* wg1p = (f16x8*)(ws + 184320);   // KT=4, NTW=40 -> 163840 B
    f16x8* wc1p = (f16x8*)(ws + 348160);   // KT=4, NTW=20 ->  81920 B
    f16x8* pfp  = (f16x8*)(ws + 430080);   // 8 frags      ->   8192 B

    pack_w<<<dim3(30), dim3(256), 0, stream>>>(wg0, wg0p, 3, 40, 128, 96);
    pack_w<<<dim3(15), dim3(256), 0, stream>>>(wc0, wc0p, 3, 20, 64, 96);
    pack_w<<<dim3(40), dim3(256), 0, stream>>>(wg1, wg1p, 4, 40, 128, 128);
    pack_w<<<dim3(20), dim3(256), 0, stream>>>(wc1, wc1p, 4, 20, 64, 128);
    pack_pcat<<<dim3(1), dim3(512), 0, stream>>>(sup, pfp);

    dcrnn_kernel<<<dim3(NBLK), dim3(1024), 0, stream>>>(
        x, wg0p, bg0, wc0p, bc0, wg1p, bg1, wc1p, bc1, pfp, fcw, fcb, out);
}